// Round 1
// baseline (635.936 us; speedup 1.0000x reference)
//
#include <hip/hip_runtime.h>
#include <cstdint>
#include <cstddef>

#define NLAB 128
#define TT   512
#define BB   512
#define MB   16        // batches per forward wave
#define PAD_ 0
#define BOS_ 1
#define EOS_ 2
#define LN2F  0.6931471805599453f
#define LOG2E 1.4426950408889634f

typedef float f32x4 __attribute__((ext_vector_type(4)));
typedef short s16x8 __attribute__((ext_vector_type(8)));

#if __has_builtin(__builtin_amdgcn_exp2f)
#define EXP2F(x) __builtin_amdgcn_exp2f(x)
#else
#define EXP2F(x) exp2f(x)
#endif

// ---- mask dtype hedge: bool(1B) vs int32(4B) -------------------------------
__device__ __forceinline__ bool mask_is_i32(const unsigned char* m8) {
    return m8[1] == 0;   // mask[0][1] always true; int32 high byte => 0
}
__device__ __forceinline__ bool mask_at(const unsigned char* m8, int idx, bool isi) {
    if (isi) return ((const int*)m8)[idx] != 0;
    return m8[idx] != 0;
}

__device__ __forceinline__ unsigned f2bf(float f) {
    union { float f; unsigned u; } v; v.f = f;
    return (v.u + 0x7FFFu + ((v.u >> 16) & 1u)) >> 16;   // RNE; inputs finite >= 0
}
__device__ __forceinline__ unsigned cvtpk(float lo, float hi) {   // bf16 pair, RNE
    unsigned r;
    asm("v_cvt_pk_bf16_f32 %0, %1, %2" : "=v"(r) : "v"(lo), "v"(hi));
    return r;
}

// ============================================================================
// Fused kernel, 64 threads/block.
//   blocks [0, 32):   forward scan — ONE WAVE owns 16 batches and ALL 128
//                     labels (8 M-tiles x 4 K-tiles = 32 mfma/step).  P lives
//                     in LDS in the same conflict-free B-frag layout as
//                     before, but the write->read round trip is within a
//                     single wave: NO barriers, no vmcnt(0) drains.  Feature
//                     loads prefetch 2 steps ahead (rings F0/F1).
//   blocks [32, 544): gold score + length for one batch each (runs on the
//                     otherwise-idle CUs, concurrent with the scan).
// ============================================================================
__global__ __launch_bounds__(64, 1) void crf_fused(
        const float* __restrict__ feats,
        const int*   __restrict__ tags,
        const unsigned char* __restrict__ m8,
        const float* __restrict__ tr,
        float* __restrict__ gold_out,
        float* __restrict__ logZ_out) {
    const int bx  = blockIdx.x;
    const bool isi = mask_is_i32(m8);

    if (bx >= BB / MB) {
        // ---------------- gold path: one batch per block --------------------
        const int b    = bx - BB / MB;
        const int lane = threadIdx.x;
        const size_t fb = (size_t)b * TT * NLAB;
        float gp = 0.f; int cnt = 0;
        for (int tt = lane; tt < TT; tt += 64) {
            const int idx = b * TT + tt;
            const bool mm = mask_at(m8, idx, isi);
            cnt += mm ? 1 : 0;
            const int tg = tags[idx];
            if (tt == 0) gp += feats[fb + tg] + tr[BOS_ * NLAB + tg];
            else if (mm) gp += feats[fb + (size_t)tt * NLAB + tg]
                             + tr[tags[idx - 1] * NLAB + tg];
        }
        #pragma unroll
        for (int off = 32; off > 0; off >>= 1) {
            gp  += __shfl_xor(gp,  off, 64);
            cnt += __shfl_xor(cnt, off, 64);
        }
        if (lane == 0)
            gold_out[b] = gp + tr[tags[b * TT + cnt - 1] * NLAB + EOS_];
        return;
    }

    // ---------------- forward path: 1 wave, 16 batches, 128 labels ----------
    const int tid = threadIdx.x;
    const int a   = tid >> 4;      // quad: K-chunk for A/B frags, row-chunk for C
    const int c   = tid & 15;      // batch column
    const int G   = bx * MB + c;

    __shared__ __align__(16) unsigned short P16[2][2048];   // P^T bf16 dbuf (8 KiB)

    // ---- lengths of the 16 batches (lane (a,c) counts quarter a of row c) --
    int cnt = 0;
    if (isi) {
        const uint4* mp = (const uint4*)((const int*)m8 + (size_t)G * TT + a * 128);
        #pragma unroll 8
        for (int i = 0; i < 32; ++i) {
            uint4 v = mp[i];
            cnt += (v.x != 0) + (v.y != 0) + (v.z != 0) + (v.w != 0);
        }
    } else {
        const uint4* mp = (const uint4*)(m8 + (size_t)G * TT + a * 128);
        #pragma unroll
        for (int i = 0; i < 8; ++i) {
            uint4 v = mp[i];
            cnt += (int)((((v.x & 0x01010101u) * 0x01010101u) >> 24)
                       + (((v.y & 0x01010101u) * 0x01010101u) >> 24)
                       + (((v.z & 0x01010101u) * 0x01010101u) >> 24)
                       + (((v.w & 0x01010101u) * 0x01010101u) >> 24));
        }
    }
    cnt += __shfl_xor(cnt, 16, 64);
    cnt += __shfl_xor(cnt, 32, 64);
    const int mylen = cnt;                  // len of batch c (same on all 4 a-lanes)
    int maxlen = mylen;
    maxlen = max(maxlen, __shfl_xor(maxlen, 1, 64));
    maxlen = max(maxlen, __shfl_xor(maxlen, 2, 64));
    maxlen = max(maxlen, __shfl_xor(maxlen, 4, 64));
    maxlen = max(maxlen, __shfl_xor(maxlen, 8, 64));
    const int mx = maxlen - 1;

    const size_t fbase = (size_t)G * TT * NLAB;

    // ---- early feature prefetch: t=1 -> F1, t=2 -> F0 (2-step-deep rings) --
    f32x4 F0[8], F1[8];
    {
        const f32x4* fp1 = (const f32x4*)(feats + fbase + (size_t)min(1, mx) * NLAB);
        const f32x4* fp2 = (const f32x4*)(feats + fbase + (size_t)min(2, mx) * NLAB);
        #pragma unroll
        for (int mt = 0; mt < 8; ++mt) { F1[mt] = fp1[4 * mt + a]; F0[mt] = fp2[4 * mt + a]; }
    }

    // ---- loop-invariant E^T A-frags: Af[mt][kt] lane holds A[m][k]=E[k][m],
    //      m = 16*mt + c, k = 32*kt + 8*a + jj   (128 VGPRs) -----------------
    s16x8 Af[8][4];
    #pragma unroll
    for (int kt = 0; kt < 4; ++kt)
        #pragma unroll
        for (int jj = 0; jj < 8; ++jj) {
            const float* tp = tr + (kt * 32 + a * 8 + jj) * NLAB + c;
            #pragma unroll
            for (int mt = 0; mt < 8; ++mt)
                Af[mt][kt][jj] = (short)f2bf(__expf(tp[mt * 16]));
        }

    // ---- t=0 init: u = tr[BOS,:] + feat0; normalize by label-3 value -------
    f32x4 pf[8];                  // lane's 32 p-values: label 16*mt+4*a+r, batch c
    float C;
    {
        f32x4 u[8];
        #pragma unroll
        for (int mt = 0; mt < 8; ++mt) {
            const f32x4 tb = *(const f32x4*)(tr + BOS_ * NLAB + mt * 16 + a * 4);
            const f32x4 ff = *(const f32x4*)(feats + fbase + mt * 16 + a * 4);
            u[mt] = tb + ff;
        }
        const float n0 = __shfl(u[0][3], c, 64);   // label 3 lives at lane (a=0,c)
        C = n0;
        #pragma unroll
        for (int mt = 0; mt < 8; ++mt)
            #pragma unroll
            for (int r = 0; r < 4; ++r)
                pf[mt][r] = __expf(u[mt][r] - n0);
    }

    const int rab = a * 16 + c;   // B-frag read element base: (kt*4+a)*16+c
    // B-frag LDS layout (unchanged, conflict-free): addr16(k,n)=((k>>3)*16+n)*8+(k&7)
    #pragma unroll
    for (int mt = 0; mt < 8; ++mt) {
        const unsigned lo = cvtpk(pf[mt][0], pf[mt][1]);
        const unsigned hi = cvtpk(pf[mt][2], pf[mt][3]);
        *(uint2*)&P16[0][((2 * mt + (a >> 1)) * 16 + c) * 8 + (a & 1) * 4]
            = make_uint2(lo, hi);
    }
    int e_cur = 0;                 // lagged per-batch pow2 scale (applied this step)
    const f32x4 zacc = {0.f, 0.f, 0.f, 0.f};

    // One recursion step.  All LDS deps are in-wave (lgkmcnt only, no barrier).
#define STEP(tcur, PBR, PBW, FF) {                                            \
    const int t_ = (tcur);                                                    \
    const bool live = t_ < mylen;                                             \
    const s16x8* PR = (const s16x8*)P16[PBR];                                 \
    const s16x8 b0 = PR[rab],       b1 = PR[64  + rab],                       \
                b2 = PR[128 + rab], b3 = PR[192 + rab];                       \
    f32x4 acc[8];                                                             \
    _Pragma("unroll")                                                         \
    for (int mt = 0; mt < 8; ++mt) {                                          \
        f32x4 a0 = __builtin_amdgcn_mfma_f32_16x16x32_bf16(Af[mt][0], b0, zacc, 0, 0, 0); \
        a0 = __builtin_amdgcn_mfma_f32_16x16x32_bf16(Af[mt][1], b1, a0, 0, 0, 0);         \
        f32x4 a1 = __builtin_amdgcn_mfma_f32_16x16x32_bf16(Af[mt][2], b2, zacc, 0, 0, 0); \
        a1 = __builtin_amdgcn_mfma_f32_16x16x32_bf16(Af[mt][3], b3, a1, 0, 0, 0);         \
        acc[mt] = a0 + a1;                                                    \
    }                                                                         \
    /* feature multiplier with scale folded into the exponent (off-chain) */  \
    const float ef_ = (float)e_cur;                                           \
    f32x4 ef2[8];                                                             \
    _Pragma("unroll")                                                         \
    for (int mt = 0; mt < 8; ++mt)                                            \
        _Pragma("unroll")                                                     \
        for (int r = 0; r < 4; ++r)                                           \
            ef2[mt][r] = EXP2F(__builtin_fmaf(FF[mt][r], LOG2E, -ef_));       \
    /* refill this ring for t+2 (raw values already consumed by ef2) */       \
    {                                                                         \
        const int tl = min(t_ + 2, mx);                                       \
        const f32x4* fp = (const f32x4*)(feats + fbase + (size_t)tl * NLAB);  \
        _Pragma("unroll")                                                     \
        for (int mt = 0; mt < 8; ++mt) FF[mt] = fp[4 * mt + a];               \
    }                                                                         \
    _Pragma("unroll")                                                         \
    for (int mt = 0; mt < 8; ++mt) {                                          \
        _Pragma("unroll")                                                     \
        for (int r = 0; r < 4; ++r) {                                         \
            const float q = acc[mt][r] * ef2[mt][r];                          \
            if (live) pf[mt][r] = q;                                          \
        }                                                                     \
        const unsigned lo = cvtpk(pf[mt][0], pf[mt][1]);                      \
        const unsigned hi = cvtpk(pf[mt][2], pf[mt][3]);                      \
        *(uint2*)&P16[PBW][((2 * mt + (a >> 1)) * 16 + c) * 8 + (a & 1) * 4]  \
            = make_uint2(lo, hi);                                             \
    }                                                                         \
    if (live) C += (float)e_cur * LN2F;                                       \
    const int se = (int)((__float_as_uint(pf[0][3]) >> 23) & 255u) - 126;     \
    e_cur = __shfl(se, c, 64);     /* label-3 exponent, lane (0,c) -> batch */ \
}

    #pragma unroll 1
    for (int t0 = 1; t0 < maxlen; t0 += 2) {
        STEP(t0,     0, 1, F1)
        STEP(t0 + 1, 1, 0, F0)      // may overrun by 1 step: all-dead, harmless
    }
#undef STEP

    // ---- logZ_b = C + log(sum_j p[j][b] * exp(tr[j,EOS])) ------------------
    float s = 0.f;
    #pragma unroll
    for (int mt = 0; mt < 8; ++mt)
        #pragma unroll
        for (int r = 0; r < 4; ++r)
            s += pf[mt][r] * __expf(tr[(mt * 16 + a * 4 + r) * NLAB + EOS_]);
    s += __shfl_xor(s, 16, 64);
    s += __shfl_xor(s, 32, 64);
    if (tid < 16) logZ_out[G] = C + __logf(s);
}

// ---- final reduction: out = mean(logZ - gold) ------------------------------
__global__ void crf_finalize(const float* __restrict__ gold,
                             const float* __restrict__ logZ,
                             float* __restrict__ out) {
    __shared__ float sh[4];
    const int i = threadIdx.x;  // 256 threads
    float v = (logZ[i] - gold[i]) + (logZ[i + 256] - gold[i + 256]);
    #pragma unroll
    for (int off = 32; off > 0; off >>= 1)
        v += __shfl_xor(v, off, 64);
    if ((i & 63) == 0) sh[i >> 6] = v;
    __syncthreads();
    if (i == 0) out[0] = (sh[0] + sh[1] + sh[2] + sh[3]) * (1.0f / (float)BB);
}

extern "C" void kernel_launch(void* const* d_in, const int* in_sizes, int n_in,
                              void* d_out, int out_size, void* d_ws, size_t ws_size,
                              hipStream_t stream) {
    const float*         feats = (const float*)d_in[0];
    const int*           tags  = (const int*)d_in[1];
    const unsigned char* m8    = (const unsigned char*)d_in[2];
    const float*         tr    = (const float*)d_in[3];

    float* gold = (float*)d_ws;       // 512 floats
    float* logZ = gold + BB;          // 512 floats
    float* out  = (float*)d_out;

    hipLaunchKernelGGL(crf_fused, dim3(BB / MB + BB), dim3(64), 0, stream,
                       feats, tags, m8, tr, gold, logZ);
    hipLaunchKernelGGL(crf_finalize, dim3(1), dim3(256), 0, stream,
                       gold, logZ, out);
}

// Round 3
// 411.088 us; speedup vs baseline: 1.5470x; 1.5470x over previous
//
#include <hip/hip_runtime.h>
#include <cstdint>
#include <cstddef>

#define NLAB 128
#define TT   512
#define BB   512
#define MB   16        // batches per forward block
#define PAD_ 0
#define BOS_ 1
#define EOS_ 2
#define LN2F  0.6931471805599453f
#define LOG2E 1.4426950408889634f

typedef float f32x4 __attribute__((ext_vector_type(4)));
typedef short s16x8 __attribute__((ext_vector_type(8)));

#if __has_builtin(__builtin_amdgcn_exp2f)
#define EXP2F(x) __builtin_amdgcn_exp2f(x)
#else
#define EXP2F(x) exp2f(x)
#endif

#define MFMA_(A,B,CV) __builtin_amdgcn_mfma_f32_16x16x32_bf16((A),(B),(CV),0,0,0)

// ---- mask dtype hedge: bool(1B) vs int32(4B) -------------------------------
__device__ __forceinline__ bool mask_is_i32(const unsigned char* m8) {
    return m8[1] == 0;   // mask[0][1] always true; int32 high byte => 0
}
__device__ __forceinline__ bool mask_at(const unsigned char* m8, int idx, bool isi) {
    if (isi) return ((const int*)m8)[idx] != 0;
    return m8[idx] != 0;
}

__device__ __forceinline__ unsigned f2bf(float f) {
    union { float f; unsigned u; } v; v.f = f;
    return (v.u + 0x7FFFu + ((v.u >> 16) & 1u)) >> 16;   // RNE; inputs finite >= 0
}
__device__ __forceinline__ unsigned cvtpk(float lo, float hi) {   // bf16 pair, RNE
    unsigned r;
    asm("v_cvt_pk_bf16_f32 %0, %1, %2" : "=v"(r) : "v"(lo), "v"(hi));
    return r;
}

// ============================================================================
// Fused kernel, 256 threads/block.
//   blocks [0, 32):    forward scan.  4 waves = 1 per SIMD of one CU.  Wave w
//                      owns M-tiles {w, w+4} (32 labels): 8 mfma + 8-elem
//                      finish per step.  P exchanged through LDS in the
//                      proven conflict-free B-frag dbuf layout; ONE
//                      __syncthreads per step (proven sync — raw s_barrier
//                      failed round 2).  Rescale exponent e is derived from
//                      the bf16 p[3] ALREADY read as b0[3] (a==0 lanes) and
//                      shfl-broadcast: no scale_sh LDS round-trip.  2^-e via
//                      bit-built float (no ldexpf libcall).  Features in an
//                      8-deep named-register ring, burst-refilled per 8 steps.
//   blocks [32, 160):  gold score + length, 4 batches/block (1 per wave).
// ============================================================================
__global__ __launch_bounds__(256, 1) void crf_fused(
        const float* __restrict__ feats,
        const int*   __restrict__ tags,
        const unsigned char* __restrict__ m8,
        const float* __restrict__ tr,
        float* __restrict__ gold_out,
        float* __restrict__ logZ_out) {
    const int bx  = blockIdx.x;
    const int tid = threadIdx.x;
    const bool isi = mask_is_i32(m8);

    if (bx >= BB / MB) {
        // ---------------- gold path: 4 batches per block ---------------------
        const int b    = (bx - BB / MB) * 4 + (tid >> 6);
        const int lane = tid & 63;
        const size_t fb = (size_t)b * TT * NLAB;
        float gp = 0.f; int cnt = 0;
        for (int tt = lane; tt < TT; tt += 64) {
            const int idx = b * TT + tt;
            const bool mm = mask_at(m8, idx, isi);
            cnt += mm ? 1 : 0;
            const int tg = tags[idx];
            if (tt == 0) gp += feats[fb + tg] + tr[BOS_ * NLAB + tg];
            else if (mm) gp += feats[fb + (size_t)tt * NLAB + tg]
                             + tr[tags[idx - 1] * NLAB + tg];
        }
        #pragma unroll
        for (int off = 32; off > 0; off >>= 1) {
            gp  += __shfl_xor(gp,  off, 64);
            cnt += __shfl_xor(cnt, off, 64);
        }
        if (lane == 0)
            gold_out[b] = gp + tr[tags[b * TT + cnt - 1] * NLAB + EOS_];
        return;
    }

    // ---------------- forward path ------------------------------------------
    const int w = tid >> 6;        // wave 0..3: owns M-tiles {w, w+4}
    const int l = tid & 63;
    const int a = l >> 4;          // K-chunk for A/B frags, row-chunk for C
    const int c = l & 15;          // batch column
    const int G = bx * MB + c;
    const size_t fbase = (size_t)G * TT * NLAB;

    __shared__ __align__(16) unsigned short P16[2][2048];   // P^T bf16 dbuf (8 KiB)
    __shared__ float red_s[4][MB];

    // ---- 8-deep feature ring, prologue fill t=1..8 (always valid: < TT) ----
    f32x4 F0a, F0b, F1a, F1b, F2a, F2b, F3a, F3b,
          F4a, F4b, F5a, F5b, F6a, F6b, F7a, F7b;
    {
        const f32x4* fp = (const f32x4*)(feats + fbase);
        const int s0 = 4 * w + a, s1 = 4 * w + 16 + a;   // f32x4 idx within row
        F0a = fp[1 * 32 + s0]; F0b = fp[1 * 32 + s1];
        F1a = fp[2 * 32 + s0]; F1b = fp[2 * 32 + s1];
        F2a = fp[3 * 32 + s0]; F2b = fp[3 * 32 + s1];
        F3a = fp[4 * 32 + s0]; F3b = fp[4 * 32 + s1];
        F4a = fp[5 * 32 + s0]; F4b = fp[5 * 32 + s1];
        F5a = fp[6 * 32 + s0]; F5b = fp[6 * 32 + s1];
        F6a = fp[7 * 32 + s0]; F6b = fp[7 * 32 + s1];
        F7a = fp[8 * 32 + s0]; F7b = fp[8 * 32 + s1];
    }

    // ---- lengths (each wave computes redundantly; no cross-wave sync) ------
    int cnt = 0;
    if (isi) {
        const uint4* mp = (const uint4*)((const int*)m8 + (size_t)G * TT + a * 128);
        #pragma unroll 8
        for (int i = 0; i < 32; ++i) {
            uint4 v = mp[i];
            cnt += (v.x != 0) + (v.y != 0) + (v.z != 0) + (v.w != 0);
        }
    } else {
        const uint4* mp = (const uint4*)(m8 + (size_t)G * TT + a * 128);
        #pragma unroll
        for (int i = 0; i < 8; ++i) {
            uint4 v = mp[i];
            cnt += (int)((((v.x & 0x01010101u) * 0x01010101u) >> 24)
                       + (((v.y & 0x01010101u) * 0x01010101u) >> 24)
                       + (((v.z & 0x01010101u) * 0x01010101u) >> 24)
                       + (((v.w & 0x01010101u) * 0x01010101u) >> 24));
        }
    }
    cnt += __shfl_xor(cnt, 16, 64);
    cnt += __shfl_xor(cnt, 32, 64);
    const int mylen = cnt;                    // len of batch c (uniform over a)
    int maxlen = mylen;
    maxlen = max(maxlen, __shfl_xor(maxlen, 1, 64));
    maxlen = max(maxlen, __shfl_xor(maxlen, 2, 64));
    maxlen = max(maxlen, __shfl_xor(maxlen, 4, 64));
    maxlen = max(maxlen, __shfl_xor(maxlen, 8, 64));
    const int mx = maxlen - 1;                // >= 255 (lengths in [T/2, T])

    // ---- loop-invariant E^T A-frags for tiles {w, w+4}: 32 VGPRs -----------
    // A[m][k] = E[k][m] = exp(tr[k][m]); lane (a,c): m = 16*mt + c,
    // k = 32*kt + 8*a + jj.
    s16x8 Af00, Af01, Af02, Af03, Af10, Af11, Af12, Af13;
    {
        s16x8* A0[4] = {&Af00, &Af01, &Af02, &Af03};
        s16x8* A1[4] = {&Af10, &Af11, &Af12, &Af13};
        #pragma unroll
        for (int kt = 0; kt < 4; ++kt)
            #pragma unroll
            for (int jj = 0; jj < 8; ++jj) {
                const float* tp = tr + (kt * 32 + a * 8 + jj) * NLAB + c;
                (*A0[kt])[jj] = (short)f2bf(__expf(tp[w * 16]));
                (*A1[kt])[jj] = (short)f2bf(__expf(tp[(w + 4) * 16]));
            }
    }

    // ---- t=0 init: u = tr[BOS,:] + feat0, normalized by label-3 value ------
    f32x4 pf0, pf1;               // lane's 8 p-values: labels 16*{w,w+4}+4a+r
    float C;
    {
        const float n0 = tr[BOS_ * NLAB + 3] + feats[fbase + 3];
        C = n0;
        const f32x4 tb0 = *(const f32x4*)(tr + BOS_ * NLAB + w * 16 + a * 4);
        const f32x4 ff0 = *(const f32x4*)(feats + fbase + w * 16 + a * 4);
        const f32x4 tb1 = *(const f32x4*)(tr + BOS_ * NLAB + (w + 4) * 16 + a * 4);
        const f32x4 ff1 = *(const f32x4*)(feats + fbase + (w + 4) * 16 + a * 4);
        #pragma unroll
        for (int r = 0; r < 4; ++r) {
            pf0[r] = __expf(tb0[r] + ff0[r] - n0);
            pf1[r] = __expf(tb1[r] + ff1[r] - n0);
        }
    }

    // B-frag LDS layout (conflict-free): addr16(k,n) = ((k>>3)*16+n)*8+(k&7)
    const int wb0 = ((2 * w       + (a >> 1)) * 16 + c) * 8 + (a & 1) * 4;
    const int wb1 = ((2 * (w + 4) + (a >> 1)) * 16 + c) * 8 + (a & 1) * 4;
    *(uint2*)&P16[0][wb0] = make_uint2(cvtpk(pf0[0], pf0[1]), cvtpk(pf0[2], pf0[3]));
    *(uint2*)&P16[0][wb1] = make_uint2(cvtpk(pf1[0], pf1[1]), cvtpk(pf1[2], pf1[3]));

    const int rab = a * 16 + c;   // B-frag read element base: (kt*4+a)*16+c
    const f32x4 zac = {0.f, 0.f, 0.f, 0.f};

    // One recursion step.  Barrier at top publishes the previous step's write
    // (and the init write for step 1).  e = exponent of bf16 p[label3]: that
    // short is b0[3] on a==0 lanes (addr16 c*8+3 <=> k=3,n=c); shfl-broadcast
    // from lane c.  Self-consistent for ANY e since q/2^e and C+=e*ln2 pair.
#define STEP(T_, Fa, Fb) {                                                    \
    __syncthreads();                                                          \
    const int PB = (T_) & 1;                                                  \
    const s16x8* PR = (const s16x8*)P16[1 - PB];                              \
    const s16x8 b0 = PR[rab],       b1 = PR[64 + rab],                        \
                b2 = PR[128 + rab], b3 = PR[192 + rab];                       \
    const int efield = ((int)(unsigned short)b0[3] >> 7) & 255;               \
    const int e = __shfl(efield, c, 64) - 126;                                \
    f32x4 x0 = MFMA_(Af00, b0, zac); x0 = MFMA_(Af01, b1, x0);                \
    f32x4 y0 = MFMA_(Af02, b2, zac); y0 = MFMA_(Af03, b3, y0);                \
    f32x4 x1 = MFMA_(Af10, b0, zac); x1 = MFMA_(Af11, b1, x1);                \
    f32x4 y1 = MFMA_(Af12, b2, zac); y1 = MFMA_(Af13, b3, y1);                \
    const float sc = __uint_as_float((unsigned)(127 - e) << 23);   /* 2^-e */ \
    const f32x4 acc0 = x0 + y0, acc1 = x1 + y1;                               \
    const bool live = (T_) < mylen;                                           \
    _Pragma("unroll")                                                         \
    for (int r = 0; r < 4; ++r) {                                             \
        const float q0 = acc0[r] * (EXP2F(Fa[r] * LOG2E) * sc);               \
        const float q1 = acc1[r] * (EXP2F(Fb[r] * LOG2E) * sc);               \
        if (live) { pf0[r] = q0; pf1[r] = q1; }                               \
    }                                                                         \
    if (live) C += (float)e * LN2F;                                           \
    *(uint2*)&P16[PB][wb0] = make_uint2(cvtpk(pf0[0], pf0[1]),                \
                                        cvtpk(pf0[2], pf0[3]));               \
    *(uint2*)&P16[PB][wb1] = make_uint2(cvtpk(pf1[0], pf1[1]),                \
                                        cvtpk(pf1[2], pf1[3]));               \
}

    #pragma unroll 1
    for (int t0 = 1; t0 < maxlen; t0 += 8) {
        const int nstep = min(8, maxlen - t0);
        STEP(t0, F0a, F0b)
        if (nstep > 1) STEP(t0 + 1, F1a, F1b)
        if (nstep > 2) STEP(t0 + 2, F2a, F2b)
        if (nstep > 3) STEP(t0 + 3, F3a, F3b)
        if (nstep > 4) STEP(t0 + 4, F4a, F4b)
        if (nstep > 5) STEP(t0 + 5, F5a, F5b)
        if (nstep > 6) STEP(t0 + 6, F6a, F6b)
        if (nstep > 7) STEP(t0 + 7, F7a, F7b)
        if (t0 + 8 < maxlen) {      // burst refill: ONE vmcnt exposure / 8 steps
            const int s0 = 4 * w + a, s1 = 4 * w + 16 + a;
            const f32x4* fp;
#define RF(i, Xa, Xb)                                                         \
            fp = (const f32x4*)(feats + fbase                                 \
                     + (size_t)min(t0 + 8 + (i), mx) * NLAB);                 \
            Xa = fp[s0]; Xb = fp[s1];
            RF(0, F0a, F0b) RF(1, F1a, F1b) RF(2, F2a, F2b) RF(3, F3a, F3b)
            RF(4, F4a, F4b) RF(5, F5a, F5b) RF(6, F6a, F6b) RF(7, F7a, F7b)
#undef RF
        }
    }
#undef STEP

    // ---- logZ_b = C + log(sum_j p[j][b] * exp(tr[j,EOS])) ------------------
    float s = 0.f;
    #pragma unroll
    for (int r = 0; r < 4; ++r) {
        s += pf0[r] * __expf(tr[(w * 16 + 4 * a + r) * NLAB + EOS_]);
        s += pf1[r] * __expf(tr[((w + 4) * 16 + 4 * a + r) * NLAB + EOS_]);
    }
    s += __shfl_xor(s, 16, 64);
    s += __shfl_xor(s, 32, 64);
    if (l < 16) red_s[w][c] = s;
    __syncthreads();
    if (tid < 16) {
        float S = red_s[0][tid] + red_s[1][tid] + red_s[2][tid] + red_s[3][tid];
        logZ_out[bx * MB + tid] = C + __logf(S);   // wave-0 lane tid: batch tid
    }
}

// ---- final reduction: out = mean(logZ - gold) ------------------------------
__global__ void crf_finalize(const float* __restrict__ gold,
                             const float* __restrict__ logZ,
                             float* __restrict__ out) {
    __shared__ float sh[4];
    const int i = threadIdx.x;  // 256 threads
    float v = (logZ[i] - gold[i]) + (logZ[i + 256] - gold[i + 256]);
    #pragma unroll
    for (int off = 32; off > 0; off >>= 1)
        v += __shfl_xor(v, off, 64);
    if ((i & 63) == 0) sh[i >> 6] = v;
    __syncthreads();
    if (i == 0) out[0] = (sh[0] + sh[1] + sh[2] + sh[3]) * (1.0f / (float)BB);
}

extern "C" void kernel_launch(void* const* d_in, const int* in_sizes, int n_in,
                              void* d_out, int out_size, void* d_ws, size_t ws_size,
                              hipStream_t stream) {
    const float*         feats = (const float*)d_in[0];
    const int*           tags  = (const int*)d_in[1];
    const unsigned char* m8    = (const unsigned char*)d_in[2];
    const float*         tr    = (const float*)d_in[3];

    float* gold = (float*)d_ws;       // 512 floats
    float* logZ = gold + BB;          // 512 floats
    float* out  = (float*)d_out;

    hipLaunchKernelGGL(crf_fused, dim3(BB / MB + BB / 4), dim3(256), 0, stream,
                       feats, tags, m8, tr, gold, logZ);
    hipLaunchKernelGGL(crf_finalize, dim3(1), dim3(256), 0, stream,
                       gold, logZ, out);
}